// Round 9
// baseline (3031.209 us; speedup 1.0000x reference)
//
#include <hip/hip_runtime.h>
#include <cstdint>
#include <cstddef>

#define BATCHN 8
#define TLEN   3200
#define NCH    512
#define BCH    128
#define HCH    512
#define LBLK   24
#define CNTF   (512.0f * 3200.0f)
#define EPSV   1e-8f
#define NSLOT  32
#define NBLK   400   // layer_k grid: 50 x 8 — must be <= co-resident capacity (512)

typedef float  floatx4 __attribute__((ext_vector_type(4)));
typedef short  short8  __attribute__((ext_vector_type(8)));
typedef short  short4v __attribute__((ext_vector_type(4)));

enum { EP_FIRST = 1, EP_LAST = 2 };

__device__ inline unsigned short f2bf(float f) {
    unsigned int u = __float_as_uint(f);
    u = (u + 0x7fffu + ((u >> 16) & 1u)) >> 16;
    return (unsigned short)u;
}
__device__ inline float bf2f(short s) {
    return __uint_as_float(((unsigned int)(unsigned short)s) << 16);
}

__device__ inline void block_reduce_atomic2(float s, float ss, float* out) {
#pragma unroll
    for (int off = 32; off; off >>= 1) {
        s  += __shfl_down(s, off, 64);
        ss += __shfl_down(ss, off, 64);
    }
    __shared__ float pr[16];
    const int wave = threadIdx.x >> 6;
    const int lane = threadIdx.x & 63;
    if (lane == 0) { pr[wave * 2] = s; pr[wave * 2 + 1] = ss; }
    __syncthreads();
    if (threadIdx.x == 0) {
        const int nw = blockDim.x >> 6;
        float a = 0.f, b = 0.f;
        for (int i = 0; i < nw; i++) { a += pr[i * 2]; b += pr[i * 2 + 1]; }
        atomicAdd(out, a);
        atomicAdd(out + 1, b);
    }
}

__device__ inline void load_stats32(const float* __restrict__ st,
                                    float& mu, float& rstd) {
    float s = 0.f, ss = 0.f;
#pragma unroll
    for (int i = 0; i < NSLOT; i++) { s += st[2 * i]; ss += st[2 * i + 1]; }
    mu = s * (1.f / CNTF);
    const float var = ss * (1.f / CNTF) - mu * mu;
    rstd = rsqrtf(var + EPSV);
}

// Coherent (device-scope) stats load — for reads AFTER the in-kernel grid
// barrier, where plain loads could hit stale per-XCD cache.
__device__ inline void load_stats32_coh(const float* st, float& mu, float& rstd) {
    float s = 0.f, ss = 0.f;
#pragma unroll
    for (int i = 0; i < NSLOT; i++) {
        s  += __hip_atomic_load(st + 2 * i,     __ATOMIC_RELAXED, __HIP_MEMORY_SCOPE_AGENT);
        ss += __hip_atomic_load(st + 2 * i + 1, __ATOMIC_RELAXED, __HIP_MEMORY_SCOPE_AGENT);
    }
    mu = s * (1.f / CNTF);
    const float var = ss * (1.f / CNTF) - mu * mu;
    rstd = rsqrtf(var + EPSV);
}

// ---------------------------------------------------------------------------
// mm_k: no-LDS MFMA GEMM (128t x 128c block, 4 waves 2x2 of 64x64) — used
// only for EP_FIRST / EP_LAST. Operand-SWAPPED MFMA: mfma(w, a) => D col =
// lane&15 -> t, row = quad*4+reg -> channel (float4/short4 epilogue).
// ---------------------------------------------------------------------------
template <int KDIM, int EP>
__global__ __launch_bounds__(256, 4) void mm_k(
    const unsigned short* __restrict__ X,
    const unsigned short* __restrict__ W,
    const float* __restrict__ bias, const float* __restrict__ uv,
    float* __restrict__ O_f32, unsigned short* __restrict__ O_bf,
    const float* __restrict__ outAcc_ro,
    const float* __restrict__ statsIn,
    const float* __restrict__ alphaPtr, int Cout)
{
    const int b    = blockIdx.z;
    const int t0   = blockIdx.x * 128;
    const int m0   = blockIdx.y * 128;
    const int lane = threadIdx.x & 63;
    const int wid  = threadIdx.x >> 6;
    const int wt   = wid & 1;
    const int wm   = wid >> 1;
    const int l15  = lane & 15;
    const int quad = lane >> 4;

    const unsigned short* Xb =
        X + ((size_t)b * TLEN + t0 + wt * 64 + l15) * KDIM + quad * 8;
    const unsigned short* Wb =
        W + (size_t)(m0 + wm * 64 + l15) * KDIM + quad * 8;

    floatx4 acc[4][4];
#pragma unroll
    for (int i = 0; i < 4; i++)
#pragma unroll
        for (int j = 0; j < 4; j++)
#pragma unroll
            for (int r = 0; r < 4; r++) acc[i][j][r] = 0.f;

#pragma unroll 2
    for (int kc = 0; kc < KDIM / 32; ++kc) {
        const int ko = kc * 32;
        short8 a[4], w[4];
#pragma unroll
        for (int i = 0; i < 4; i++)
            a[i] = *reinterpret_cast<const short8*>(Xb + (size_t)i * 16 * KDIM + ko);
#pragma unroll
        for (int j = 0; j < 4; j++)
            w[j] = *reinterpret_cast<const short8*>(Wb + (size_t)j * 16 * KDIM + ko);
#pragma unroll
        for (int i = 0; i < 4; i++)
#pragma unroll
            for (int j = 0; j < 4; j++)
                acc[i][j] = __builtin_amdgcn_mfma_f32_16x16x32_bf16(
                    w[j], a[i], acc[i][j], 0, 0, 0);
    }

    float mu = 0.f, rstd = 1.f, alpha = 0.f;
    load_stats32(statsIn + b * (2 * NSLOT), mu, rstd);
    if (EP == EP_LAST) alpha = alphaPtr[0];

#pragma unroll
    for (int j = 0; j < 4; j++) {
        const int cb = m0 + wm * 64 + j * 16 + quad * 4;   // 4 consecutive c
        const float4 b4 = *reinterpret_cast<const float4*>(bias + cb);
        const float4 u4 = *reinterpret_cast<const float4*>(uv + cb);
        const float4 v4 = *reinterpret_cast<const float4*>(
            uv + cb + (EP == EP_LAST ? 2 * BCH : Cout));
        float rb[4] = { b4.x + u4.x - mu * rstd * v4.x,
                        b4.y + u4.y - mu * rstd * v4.y,
                        b4.z + u4.z - mu * rstd * v4.z,
                        b4.w + u4.w - mu * rstd * v4.w };
#pragma unroll
        for (int i = 0; i < 4; i++) {
            const int t = t0 + wt * 64 + i * 16 + l15;
            const size_t idx = ((size_t)b * TLEN + t) * Cout + cb;
            if (EP == EP_FIRST) {
                float4 o;
                short4v s;
#pragma unroll
                for (int r = 0; r < 4; r++) {
                    const float val = rstd * acc[i][j][r] + rb[r];
                    (&o.x)[r] = val;
                    s[r] = (short)f2bf(val);
                }
                *reinterpret_cast<float4*>(O_f32 + idx) = o;
                *reinterpret_cast<short4v*>(O_bf + idx) = s;
            } else {   // EP_LAST
                const float4 oa = *reinterpret_cast<const float4*>(outAcc_ro + idx);
                short4v s;
#pragma unroll
                for (int r = 0; r < 4; r++) {
                    const float val = rstd * acc[i][j][r] + rb[r];
                    const float f = (&oa.x)[r] + val;
                    const float pv = f >= 0.f ? f : alpha * f;
                    s[r] = (short)f2bf(pv);
                }
                *reinterpret_cast<short4v*>(O_bf + idx) = s;
            }
        }
    }
}

// ---------------------------------------------------------------------------
// EP_H GEMM with LDS-staged A (layer 0 only): h = PReLU(W1 @ feats + b1).
// ---------------------------------------------------------------------------
__device__ inline void gload_lds16(const unsigned short* g, unsigned short* l) {
    __builtin_amdgcn_global_load_lds(
        (const __attribute__((address_space(1))) unsigned int*)(g),
        (__attribute__((address_space(3))) unsigned int*)(l),
        16, 0, 0);
}

__global__ __launch_bounds__(256, 4) void mm_h_lds_k(
    const unsigned short* __restrict__ X,   // feats_bf [b][t][128]
    const unsigned short* __restrict__ W,   // W1b [512][128]
    const float* __restrict__ bias,
    float* __restrict__ statsOut,
    const float* __restrict__ alphaPtr,
    unsigned short* __restrict__ O_bf)      // h [b][t][512]
{
    __shared__ unsigned short As[128 * 128];  // 32KB
    const int b    = blockIdx.z;
    const int t0   = blockIdx.x * 128;
    const int m0   = blockIdx.y * 128;
    const int lane = threadIdx.x & 63;
    const int wid  = threadIdx.x >> 6;
    const int wt   = wid & 1;
    const int wm   = wid >> 1;
    const int l15  = lane & 15;
    const int quad = lane >> 4;

#pragma unroll
    for (int q = 0; q < 8; q++) {
        const int r = wid * 32 + q * 4 + quad;
        const unsigned short* src =
            X + ((size_t)b * TLEN + t0 + r) * BCH + ((l15 ^ (r & 15)) * 8);
        gload_lds16(src, As + (wid * 32 + q * 4) * BCH);
    }
    __syncthreads();

    const unsigned short* Wb =
        W + (size_t)(m0 + wm * 64 + l15) * BCH + quad * 8;

    floatx4 acc[4][4];
#pragma unroll
    for (int i = 0; i < 4; i++)
#pragma unroll
        for (int j = 0; j < 4; j++)
#pragma unroll
            for (int r = 0; r < 4; r++) acc[i][j][r] = 0.f;

#pragma unroll
    for (int kc = 0; kc < 4; ++kc) {
        short8 a[4], w[4];
#pragma unroll
        for (int j = 0; j < 4; j++)
            w[j] = *reinterpret_cast<const short8*>(
                Wb + (size_t)j * 16 * BCH + kc * 32);
#pragma unroll
        for (int i = 0; i < 4; i++) {
            const int R  = wt * 64 + i * 16 + l15;     // R&15 == l15
            const int sl = (kc * 4 + quad) ^ l15;
            a[i] = *reinterpret_cast<const short8*>(As + R * BCH + sl * 8);
        }
#pragma unroll
        for (int i = 0; i < 4; i++)
#pragma unroll
            for (int j = 0; j < 4; j++)
                acc[i][j] = __builtin_amdgcn_mfma_f32_16x16x32_bf16(
                    w[j], a[i], acc[i][j], 0, 0, 0);
    }

    const float alpha = alphaPtr[0];
    float ssum = 0.f, ssq = 0.f;
#pragma unroll
    for (int j = 0; j < 4; j++) {
        const int cb = m0 + wm * 64 + j * 16 + quad * 4;   // 4 consecutive c
        const float4 b4 = *reinterpret_cast<const float4*>(bias + cb);
#pragma unroll
        for (int i = 0; i < 4; i++) {
            const int t = t0 + wt * 64 + i * 16 + l15;
            short4v s;
#pragma unroll
            for (int r = 0; r < 4; r++) {
                float val = acc[i][j][r] + (&b4.x)[r];
                val = val >= 0.f ? val : alpha * val;
                ssum += val; ssq += val * val;
                s[r] = (short)f2bf(val);
            }
            *reinterpret_cast<short4v*>(
                O_bf + ((size_t)b * TLEN + t) * HCH + cb) = s;
        }
    }
    block_reduce_atomic2(ssum, ssq,
        statsOut + b * (2 * NSLOT) +
        ((blockIdx.x + blockIdx.y * 25) & (NSLOT - 1)) * 2);
}

// ---------------------------------------------------------------------------
// MEGA layer kernel: dwconv(i) + dual(i) + mm_h(i+1) in ONE dispatch.
// 512 threads (8 waves), 64t rows per block, grid (50,1,8) = 400 blocks
// (co-resident: 2 blocks/CU x 256 CU = 512 >= 400, launch_bounds(512,4),
// LDS 64KB -> LDS-limited to exactly 2/CU).
//   Phase D: depthwise conv for the block's 64 rows, all 512 ch, written
//            straight into the 64KB LDS tile (swizzled) + atomic hd-stats.
//            Eliminates the hd global round-trip (52 MB/layer).
//   Grid barrier (spin on device-scope counter): hd-stats complete.
//   Phase B: dual GEMM from LDS (no K-loop barriers — tile is resident),
//            skip->outAcc RMW, res->feats RMW + bf16 deposit to LDS.
//   Phase 2: mm_h(i+1) from the deposited feats tile -> h (IN-PLACE: all
//            phase-D h reads precede the grid barrier, all phase-2 h
//            writes follow it).
// ---------------------------------------------------------------------------
__global__ __launch_bounds__(512, 4) void layer_k(
    unsigned short* __restrict__ h,          // h(i) in, h(i+1) out (in-place)
    const float* __restrict__ Wd, const float* __restrict__ bd,
    const float* __restrict__ g1v, const float* __restrict__ be1v,
    const float* __restrict__ st_h_in, const float* __restrict__ a2p, int dil,
    const unsigned short* __restrict__ Wsr,
    const float* __restrict__ bskip, const float* __restrict__ bres,
    const float* __restrict__ uv,
    float* __restrict__ st_hd, unsigned int* __restrict__ ctr,
    float* __restrict__ feats, float* __restrict__ outAcc,
    const unsigned short* __restrict__ W1,
    const float* __restrict__ b1, const float* __restrict__ a1p,
    float* __restrict__ st_h_next)
{
    __shared__ unsigned short As[4 * 64 * 128];   // 64KB: 4 K-chunks x [64][128]
    const int b    = blockIdx.z;
    const int t0   = blockIdx.x * 64;
    const int lane = threadIdx.x & 63;
    const int wv   = threadIdx.x >> 6;   // 0..7
    const int l15  = lane & 15;
    const int quad = lane >> 4;

    // ---------------- phase D: depthwise conv -> LDS tile ----------------
    {
        float mu1, rstd1;
        load_stats32(st_h_in + b * (2 * NSLOT), mu1, rstd1);  // prev dispatch: plain ok
        const float alpha = a2p[0];
        const int c0 = lane * 8;
        float g[8], be[8], bz[8], wall[24];
#pragma unroll
        for (int qq = 0; qq < 6; qq++) {
            const float4 w4 = *reinterpret_cast<const float4*>(Wd + (size_t)c0 * 3 + qq * 4);
            wall[qq * 4 + 0] = w4.x; wall[qq * 4 + 1] = w4.y;
            wall[qq * 4 + 2] = w4.z; wall[qq * 4 + 3] = w4.w;
        }
        {
            const float4 ga = *reinterpret_cast<const float4*>(g1v + c0);
            const float4 gb = *reinterpret_cast<const float4*>(g1v + c0 + 4);
            const float4 ba = *reinterpret_cast<const float4*>(be1v + c0);
            const float4 bb = *reinterpret_cast<const float4*>(be1v + c0 + 4);
            const float4 da = *reinterpret_cast<const float4*>(bd + c0);
            const float4 db = *reinterpret_cast<const float4*>(bd + c0 + 4);
            const float gg[8]  = { ga.x, ga.y, ga.z, ga.w, gb.x, gb.y, gb.z, gb.w };
            const float bbv[8] = { ba.x, ba.y, ba.z, ba.w, bb.x, bb.y, bb.z, bb.w };
            const float dd[8]  = { da.x, da.y, da.z, da.w, db.x, db.y, db.z, db.w };
#pragma unroll
            for (int jj = 0; jj < 8; jj++) {
                g[jj]  = gg[jj] * rstd1;
                be[jj] = bbv[jj] - mu1 * rstd1 * gg[jj];
                bz[jj] = dd[jj];
            }
        }
        float psum = 0.f, psq = 0.f;
        const int chunk = c0 >> 7;
        const int cc    = c0 & 127;
#pragma unroll
        for (int q = 0; q < 8; ++q) {
            const int rl = wv * 8 + q;            // 8 waves x 8 rows = 64
            const int t  = t0 + rl;
            const size_t rowb = ((size_t)b * TLEN + t) * HCH + c0;
            const bool hasP = (t - dil) >= 0;
            const bool hasN = (t + dil) < TLEN;
            const short8 cur = *reinterpret_cast<const short8*>(h + rowb);
            short8 prv = {}, nxt = {};
            if (hasP) prv = *reinterpret_cast<const short8*>(h + rowb - (size_t)dil * HCH);
            if (hasN) nxt = *reinterpret_cast<const short8*>(h + rowb + (size_t)dil * HCH);
            short8 o;
#pragma unroll
            for (int jj = 0; jj < 8; jj++) {
                float a0 = bz[jj] + wall[jj * 3 + 1] * (g[jj] * bf2f(cur[jj]) + be[jj]);
                if (hasP) a0 += wall[jj * 3 + 0] * (g[jj] * bf2f(prv[jj]) + be[jj]);
                if (hasN) a0 += wall[jj * 3 + 2] * (g[jj] * bf2f(nxt[jj]) + be[jj]);
                const float v = a0 >= 0.f ? a0 : alpha * a0;
                o[jj] = (short)f2bf(v);
                psum += v; psq += v * v;
            }
            // swizzled store: chunk-major, slot = (cc>>3) ^ (row&15)
            *reinterpret_cast<short8*>(
                As + chunk * 8192 + rl * 128 + (((cc >> 3) ^ (rl & 15)) * 8)) = o;
        }
        block_reduce_atomic2(psum, psq,
            st_hd + b * (2 * NSLOT) + (blockIdx.x & (NSLOT - 1)) * 2);
    }

    // ---------------- grid-wide spin barrier (hd-stats complete) ----------
    __syncthreads();
    if (threadIdx.x == 0) {
        __hip_atomic_fetch_add(ctr, 1u, __ATOMIC_ACQ_REL, __HIP_MEMORY_SCOPE_AGENT);
        unsigned int v;
        do {
            __builtin_amdgcn_s_sleep(2);
            v = __hip_atomic_load(ctr, __ATOMIC_ACQUIRE, __HIP_MEMORY_SCOPE_AGENT);
        } while (v < (unsigned)NBLK);
    }
    __syncthreads();

    // ---------------- phase B: dual GEMM from LDS ----------------
    float mu, rstd;
    load_stats32_coh(st_hd + b * (2 * NSLOT), mu, rstd);

    const unsigned short* Wb =
        Wsr + (size_t)(wv * 32 + l15) * HCH + quad * 8;

    floatx4 acc[4][2];
#pragma unroll
    for (int i = 0; i < 4; i++)
#pragma unroll
        for (int j = 0; j < 2; j++)
#pragma unroll
            for (int r = 0; r < 4; r++) acc[i][j][r] = 0.f;

#pragma unroll
    for (int kc = 0; kc < 4; ++kc) {
        const unsigned short* Ab = As + kc * 8192;
#pragma unroll
        for (int ks = 0; ks < 4; ++ks) {
            short8 a[4], w[2];
#pragma unroll
            for (int j = 0; j < 2; j++)
                w[j] = *reinterpret_cast<const short8*>(
                    Wb + (size_t)j * 16 * HCH + kc * 128 + ks * 32);
#pragma unroll
            for (int i = 0; i < 4; i++) {
                const int R  = i * 16 + l15;          // R&15 == l15
                const int sl = (ks * 4 + quad) ^ l15;
                a[i] = *reinterpret_cast<const short8*>(Ab + R * 128 + sl * 8);
            }
#pragma unroll
            for (int i = 0; i < 4; i++)
#pragma unroll
                for (int j = 0; j < 2; j++)
                    acc[i][j] = __builtin_amdgcn_mfma_f32_16x16x32_bf16(
                        w[j], a[i], acc[i][j], 0, 0, 0);
        }
    }
    __syncthreads();   // all As reads done before deposit overwrites chunk 0

    const bool sk = (wv < 4);            // wave-uniform
#pragma unroll
    for (int j = 0; j < 2; j++) {
        const int c  = wv * 32 + j * 16 + quad * 4;  // 0..255 combined
        const int cc = sk ? c : c - 128;
        const float4 b4 = sk
            ? *reinterpret_cast<const float4*>(bskip + cc)
            : *reinterpret_cast<const float4*>(bres + cc);
        const float4 u4 = *reinterpret_cast<const float4*>(uv + c);
        const float4 v4 = *reinterpret_cast<const float4*>(uv + c + 256);
        float rb[4] = { b4.x + u4.x - mu * rstd * v4.x,
                        b4.y + u4.y - mu * rstd * v4.y,
                        b4.z + u4.z - mu * rstd * v4.z,
                        b4.w + u4.w - mu * rstd * v4.w };
#pragma unroll
        for (int i = 0; i < 4; i++) {
            const int t = t0 + i * 16 + l15;
            const size_t idx = ((size_t)b * TLEN + t) * BCH + cc;
            if (sk) {
                float4 oa = *reinterpret_cast<const float4*>(outAcc + idx);
#pragma unroll
                for (int r = 0; r < 4; r++)
                    (&oa.x)[r] += rstd * acc[i][j][r] + rb[r];
                *reinterpret_cast<float4*>(outAcc + idx) = oa;
            } else {
                float4 f = *reinterpret_cast<const float4*>(feats + idx);
                short4v s;
#pragma unroll
                for (int r = 0; r < 4; r++) {
                    (&f.x)[r] += rstd * acc[i][j][r] + rb[r];
                    s[r] = (short)f2bf((&f.x)[r]);
                }
                *reinterpret_cast<float4*>(feats + idx) = f;
                // deposit feats tile into As chunk 0, staging swizzle
                const int row = i * 16 + l15;           // row&15 == l15
                const int sl  = (cc >> 3) ^ l15;
                *reinterpret_cast<short4v*>(
                    As + row * 128 + sl * 8 + (cc & 7)) = s;
            }
        }
    }
    __syncthreads();

    // ---------------- phase 2: h(i+1) = PReLU(W1 @ feats_tile + b1) -------
    const float alpha1 = a1p[0];
    float ssum = 0.f, ssq = 0.f;
    const int mb = wv * 64;              // 8 waves x 64 m = 512
    const unsigned short* W1p =
        W1 + (size_t)(mb + l15) * BCH + quad * 8;

    floatx4 acc2[4][4];
#pragma unroll
    for (int i = 0; i < 4; i++)
#pragma unroll
        for (int j = 0; j < 4; j++)
#pragma unroll
            for (int r = 0; r < 4; r++) acc2[i][j][r] = 0.f;

#pragma unroll
    for (int kc = 0; kc < 4; ++kc) {
        short8 a[4], w[4];
#pragma unroll
        for (int j = 0; j < 4; j++)
            w[j] = *reinterpret_cast<const short8*>(
                W1p + (size_t)j * 16 * BCH + kc * 32);
#pragma unroll
        for (int i = 0; i < 4; i++) {
            const int R  = i * 16 + l15;
            const int sl = (kc * 4 + quad) ^ l15;
            a[i] = *reinterpret_cast<const short8*>(As + R * 128 + sl * 8);
        }
#pragma unroll
        for (int i = 0; i < 4; i++)
#pragma unroll
            for (int j = 0; j < 4; j++)
                acc2[i][j] = __builtin_amdgcn_mfma_f32_16x16x32_bf16(
                    w[j], a[i], acc2[i][j], 0, 0, 0);
    }

#pragma unroll
    for (int j = 0; j < 4; j++) {
        const int cb = mb + j * 16 + quad * 4;
        const float4 b4 = *reinterpret_cast<const float4*>(b1 + cb);
#pragma unroll
        for (int i = 0; i < 4; i++) {
            const int t = t0 + i * 16 + l15;
            short4v s;
#pragma unroll
            for (int r = 0; r < 4; r++) {
                float val = acc2[i][j][r] + (&b4.x)[r];
                val = val >= 0.f ? val : alpha1 * val;
                ssum += val; ssq += val * val;
                s[r] = (short)f2bf(val);
            }
            *reinterpret_cast<short4v*>(
                h + ((size_t)b * TLEN + t) * HCH + cb) = s;
        }
    }
    block_reduce_atomic2(ssum, ssq,
        st_h_next + b * (2 * NSLOT) + (blockIdx.x & (NSLOT - 1)) * 2);
}

// Final GEMM: out[b][m][t] = sigmoid(Wo @ Xbf + bo).
__global__ __launch_bounds__(256, 4) void mm_final_k(
    const unsigned short* __restrict__ Xbf, const unsigned short* __restrict__ Wb,
    const float* __restrict__ bo, float* __restrict__ out)
{
    const int b    = blockIdx.z;
    const int t0   = blockIdx.x * 128;
    const int m0   = blockIdx.y * 128;
    const int lane = threadIdx.x & 63;
    const int wid  = threadIdx.x >> 6;
    const int wc   = wid & 1;    // t half
    const int wr   = wid >> 1;   // m half
    const int l15  = lane & 15;
    const int quad = lane >> 4;

    const unsigned short* Wp =
        Wb + (size_t)(m0 + wr * 64 + l15) * BCH + quad * 8;
    const unsigned short* Xp =
        Xbf + ((size_t)b * TLEN + t0 + wc * 64 + l15) * BCH + quad * 8;

    floatx4 acc[4][4];
#pragma unroll
    for (int i = 0; i < 4; i++)
#pragma unroll
        for (int j = 0; j < 4; j++)
#pragma unroll
            for (int r = 0; r < 4; r++) acc[i][j][r] = 0.f;

#pragma unroll 2
    for (int kc = 0; kc < BCH / 32; ++kc) {
        const int ko = kc * 32;
        short8 a[4], x[4];
#pragma unroll
        for (int i = 0; i < 4; i++)
            a[i] = *reinterpret_cast<const short8*>(Wp + (size_t)i * 16 * BCH + ko);
#pragma unroll
        for (int j = 0; j < 4; j++)
            x[j] = *reinterpret_cast<const short8*>(Xp + (size_t)j * 16 * BCH + ko);
#pragma unroll
        for (int i = 0; i < 4; i++)
#pragma unroll
            for (int j = 0; j < 4; j++)
                acc[i][j] = __builtin_amdgcn_mfma_f32_16x16x32_bf16(
                    a[i], x[j], acc[i][j], 0, 0, 0);
    }

#pragma unroll
    for (int i = 0; i < 4; i++) {
        const int mb = m0 + wr * 64 + i * 16 + quad * 4;
#pragma unroll
        for (int r = 0; r < 4; r++) {
            const int m = mb + r;
            const float bz = bo[m];
#pragma unroll
            for (int j = 0; j < 4; j++) {
                const int t = t0 + wc * 64 + j * 16 + l15;
                const float val = acc[i][j][r] + bz;
                const float e = __expf(-val);
                out[((size_t)b * (2 * NCH) + m) * TLEN + t] =
                    __builtin_amdgcn_rcpf(1.f + e);
            }
        }
    }
}

// Weight prep: bf16 convert with optional per-column gLN gamma fold, plus
// u = W @ be, v = W @ g row-vectors. One wave per row.
__global__ __launch_bounds__(256) void prep_w_k(
    const float* __restrict__ W, const float* __restrict__ g,
    const float* __restrict__ be, unsigned short* __restrict__ Wout,
    float* __restrict__ uv, int Mrows, int K, int nmat, int Mout, int rowOff)
{
    const int r    = blockIdx.x * 4 + (threadIdx.x >> 6);
    const int lane = threadIdx.x & 63;
    if (r >= Mrows * nmat) return;
    const int mat = r / Mrows;
    const int m   = r - mat * Mrows;
    const float* Wrow = W + (size_t)r * K;
    const float* gv = g  ? g  + (size_t)mat * K : nullptr;
    const float* bv = be ? be + (size_t)mat * K : nullptr;
    unsigned short* orow = Wout + ((size_t)mat * Mout + rowOff + m) * K;
    float u = 0.f, v = 0.f;
    for (int k = lane * 4; k < K; k += 256) {
        float4 w4 = *reinterpret_cast<const float4*>(Wrow + k);
        float4 o4 = w4;
        if (gv) {
            const float4 g4 = *reinterpret_cast<const float4*>(gv + k);
            const float4 b4 = *reinterpret_cast<const float4*>(bv + k);
            o4.x = w4.x * g4.x; o4.y = w4.y * g4.y;
            o4.z = w4.z * g4.z; o4.w = w4.w * g4.w;
            u += w4.x * b4.x + w4.y * b4.y + w4.z * b4.z + w4.w * b4.w;
            v += w4.x * g4.x + w4.y * g4.y + w4.z * g4.z + w4.w * g4.w;
        }
        short4v s;
        s[0] = (short)f2bf(o4.x); s[1] = (short)f2bf(o4.y);
        s[2] = (short)f2bf(o4.z); s[3] = (short)f2bf(o4.w);
        *reinterpret_cast<short4v*>(orow + k) = s;
    }
    if (gv && uv) {
#pragma unroll
        for (int off = 32; off; off >>= 1) {
            u += __shfl_down(u, off, 64);
            v += __shfl_down(v, off, 64);
        }
        if (lane == 0) {
            uv[(size_t)mat * 2 * Mout + rowOff + m]        = u;
            uv[(size_t)mat * 2 * Mout + Mout + rowOff + m] = v;
        }
    }
}

// Transpose + bf16 cvt + x-stats (fused).
__global__ __launch_bounds__(256) void tr_x_k(
    const float* __restrict__ x, unsigned short* __restrict__ xt,
    float* __restrict__ statsOut)
{
    __shared__ unsigned short tile[32][33];
    const int b  = blockIdx.z;
    const int t0 = blockIdx.x * 32;
    const int c0 = blockIdx.y * 32;
    const int tx = threadIdx.x & 31;
    const int ty = threadIdx.x >> 5;

    float s = 0.f, ss = 0.f;
#pragma unroll
    for (int r = 0; r < 4; r++) {
        const int cl = ty + r * 8;
        const float v = x[((size_t)b * NCH + c0 + cl) * TLEN + t0 + tx];
        s += v; ss += v * v;
        tile[tx][cl] = f2bf(v);
    }
    __syncthreads();
#pragma unroll
    for (int r = 0; r < 4; r++) {
        const int tl = ty + r * 8;
        xt[((size_t)b * TLEN + t0 + tl) * NCH + c0 + tx] = tile[tl][tx];
    }
    block_reduce_atomic2(s, ss,
        statsOut + b * (2 * NSLOT) +
        ((blockIdx.x + blockIdx.y * 25) & (NSLOT - 1)) * 2);
}

// Depthwise dilated conv (layer 23 only), gLN folded, + bd, PReLU(a2), stats.
__global__ __launch_bounds__(256) void dwconv_k(
    const unsigned short* __restrict__ h, unsigned short* __restrict__ hd,
    const float* __restrict__ Wd, const float* __restrict__ bd,
    const float* __restrict__ g1, const float* __restrict__ be1,
    const float* __restrict__ statsIn, float* __restrict__ statsOut,
    const float* __restrict__ a2p, int dil)
{
    const int b  = blockIdx.y;
    const int tb = blockIdx.x * 16 + (threadIdx.x >> 6) * 4;
    const int c0 = (threadIdx.x & 63) * 8;

    float mu, rstd;
    load_stats32(statsIn + b * (2 * NSLOT), mu, rstd);
    const float alpha = a2p[0];

    float g[8], be[8], bz[8], wall[24];
#pragma unroll
    for (int q = 0; q < 6; q++) {
        const float4 w4 = *reinterpret_cast<const float4*>(Wd + (size_t)c0 * 3 + q * 4);
        wall[q * 4 + 0] = w4.x; wall[q * 4 + 1] = w4.y;
        wall[q * 4 + 2] = w4.z; wall[q * 4 + 3] = w4.w;
    }
    {
        const float4 ga = *reinterpret_cast<const float4*>(g1 + c0);
        const float4 gb = *reinterpret_cast<const float4*>(g1 + c0 + 4);
        const float4 ba = *reinterpret_cast<const float4*>(be1 + c0);
        const float4 bb = *reinterpret_cast<const float4*>(be1 + c0 + 4);
        const float4 da = *reinterpret_cast<const float4*>(bd + c0);
        const float4 db = *reinterpret_cast<const float4*>(bd + c0 + 4);
        const float gg[8] = { ga.x, ga.y, ga.z, ga.w, gb.x, gb.y, gb.z, gb.w };
        const float bbv[8] = { ba.x, ba.y, ba.z, ba.w, bb.x, bb.y, bb.z, bb.w };
        const float dd[8] = { da.x, da.y, da.z, da.w, db.x, db.y, db.z, db.w };
#pragma unroll
        for (int jj = 0; jj < 8; jj++) {
            g[jj]  = gg[jj] * rstd;
            be[jj] = bbv[jj] - mu * rstd * gg[jj];
            bz[jj] = dd[jj];
        }
    }

    float psum = 0.f, psq = 0.f;
#pragma unroll
    for (int it = 0; it < 4; ++it) {
        const int t = tb + it;
        const size_t rowb = ((size_t)b * TLEN + t) * HCH + c0;
        const bool hasP = (t - dil) >= 0;
        const bool hasN = (t + dil) < TLEN;
        const short8 cur = *reinterpret_cast<const short8*>(h + rowb);
        short8 prv = {}, nxt = {};
        if (hasP) prv = *reinterpret_cast<const short8*>(h + rowb - (size_t)dil * HCH);
        if (hasN) nxt = *reinterpret_cast<const short8*>(h + rowb + (size_t)dil * HCH);

        short8 o;
#pragma unroll
        for (int jj = 0; jj < 8; jj++) {
            float acc = bz[jj] + wall[jj * 3 + 1] * (g[jj] * bf2f(cur[jj]) + be[jj]);
            if (hasP) acc += wall[jj * 3 + 0] * (g[jj] * bf2f(prv[jj]) + be[jj]);
            if (hasN) acc += wall[jj * 3 + 2] * (g[jj] * bf2f(nxt[jj]) + be[jj]);
            const float v = acc >= 0.f ? acc : alpha * acc;
            o[jj] = (short)f2bf(v);
            psum += v; psq += v * v;
        }
        *reinterpret_cast<short8*>(hd + rowb) = o;
    }
    block_reduce_atomic2(psum, psq,
        statsOut + b * (2 * NSLOT) + (blockIdx.x & (NSLOT - 1)) * 2);
}

extern "C" void kernel_launch(void* const* d_in, const int* in_sizes, int n_in,
                              void* d_out, int out_size, void* d_ws, size_t ws_size,
                              hipStream_t stream)
{
    (void)in_sizes; (void)n_in; (void)out_size; (void)ws_size;

    const float* x    = (const float*)d_in[0];
    const float* in_g = (const float*)d_in[1];
    const float* in_b = (const float*)d_in[2];
    const float* Wc   = (const float*)d_in[3];
    const float* bc   = (const float*)d_in[4];
    const float* W1   = (const float*)d_in[5];
    const float* b1   = (const float*)d_in[6];
    const float* a1   = (const float*)d_in[7];
    const float* g1   = (const float*)d_in[8];
    const float* be1  = (const float*)d_in[9];
    const float* Wd   = (const float*)d_in[10];
    const float* bd   = (const float*)d_in[11];
    const float* a2   = (const float*)d_in[12];
    const float* g2   = (const float*)d_in[13];
    const float* be2  = (const float*)d_in[14];
    const float* Wres = (const float*)d_in[15];
    const float* bres = (const float*)d_in[16];
    const float* Wskip= (const float*)d_in[17];
    const float* bskip= (const float*)d_in[18];
    const float* aout = (const float*)d_in[19];
    const float* Wo   = (const float*)d_in[20];
    const float* bo   = (const float*)d_in[21];
    float* out = (float*)d_out;

    // workspace carve-up (bytes, 16B-aligned regions)
    uint8_t* p = (uint8_t*)d_ws;
    unsigned short* x_t      = (unsigned short*)p; p += (size_t)BATCHN*TLEN*NCH*2;
    float*          feats    = (float*)p;          p += (size_t)BATCHN*TLEN*BCH*4;
    unsigned short* feats_bf = (unsigned short*)p; p += (size_t)BATCHN*TLEN*BCH*2;
    float*          outAcc   = (float*)p;          p += (size_t)BATCHN*TLEN*BCH*4;
    unsigned short* h        = (unsigned short*)p; p += (size_t)BATCHN*TLEN*HCH*2;
    unsigned short* hd       = (unsigned short*)p; p += (size_t)BATCHN*TLEN*HCH*2;
    unsigned short* WcG      = (unsigned short*)p; p += (size_t)BCH*NCH*2;
    unsigned short* W1b      = (unsigned short*)p; p += (size_t)LBLK*HCH*BCH*2;
    unsigned short* Wsr      = (unsigned short*)p; p += (size_t)LBLK*256*HCH*2;
    unsigned short* Wob      = (unsigned short*)p; p += (size_t)(2*NCH)*BCH*2;
    float*          uv_c     = (float*)p;          p += (size_t)2*BCH*4;
    float*          uv_sr    = (float*)p;          p += (size_t)LBLK*2*256*4;
    float*          stats    = (float*)p;

    const size_t SLOTF = (size_t)BATCHN * 2 * NSLOT;  // floats per stat slot
    unsigned int* ctrs = (unsigned int*)(stats + 49 * SLOTF);

    hipMemsetAsync(stats, 0,
                   (size_t)49 * SLOTF * sizeof(float) + 32 * sizeof(unsigned int),
                   stream);
    hipMemsetAsync(outAcc, 0, (size_t)BATCHN*TLEN*BCH*sizeof(float), stream);

    // ---- prep ----
    tr_x_k<<<dim3(100, 16, BATCHN), 256, 0, stream>>>(x, x_t, stats);
    prep_w_k<<<32,   256, 0, stream>>>(Wc,   in_g,    in_b,    WcG, uv_c, BCH,   NCH, 1,      BCH, 0);
    prep_w_k<<<3072, 256, 0, stream>>>(W1,   nullptr, nullptr, W1b, nullptr, HCH, BCH, LBLK,  HCH, 0);
    prep_w_k<<<768,  256, 0, stream>>>(Wskip,g2,      be2,     Wsr, uv_sr, BCH,  HCH, LBLK,   256, 0);
    prep_w_k<<<736,  256, 0, stream>>>(Wres, g2,      be2,     Wsr, uv_sr, BCH,  HCH, LBLK-1, 256, 128);
    prep_w_k<<<256,  256, 0, stream>>>(Wo,   nullptr, nullptr, Wob, nullptr, 2*NCH, BCH, 1,   2*NCH, 0);

    // ---- first: feats = rstd*(WcG @ x_t) + rowbias ----
    mm_k<NCH, EP_FIRST><<<dim3(25, 1, BATCHN), 256, 0, stream>>>(
        x_t, WcG, bc, uv_c, feats, feats_bf, nullptr, stats, nullptr, BCH);

    // ---- layer 0 mm_h (standalone) ----
    mm_h_lds_k<<<dim3(25, 4, BATCHN), 256, 0, stream>>>(
        feats_bf, W1b, b1, stats + SLOTF, a1, h);

    for (int i = 0; i < LBLK; i++) {
        float* st_h  = stats + (size_t)(1 + 2 * i) * SLOTF;
        float* st_hd = stats + (size_t)(2 + 2 * i) * SLOTF;
        const int dil = 1 << (i & 7);

        if (i < LBLK - 1) {
            layer_k<<<dim3(50, 1, BATCHN), 512, 0, stream>>>(
                h,
                Wd + (size_t)i * HCH * 3, bd + (size_t)i * HCH,
                g1 + (size_t)i * HCH, be1 + (size_t)i * HCH,
                st_h, a2 + i, dil,
                Wsr + (size_t)i * 256 * HCH,
                bskip + (size_t)i * BCH, bres + (size_t)i * BCH,
                uv_sr + (size_t)i * 2 * 256,
                st_hd, ctrs + i,
                feats, outAcc,
                W1b + (size_t)(i + 1) * HCH * BCH,
                b1 + (size_t)(i + 1) * HCH, a1 + (i + 1),
                stats + (size_t)(1 + 2 * (i + 1)) * SLOTF);
        } else {
            dwconv_k<<<dim3(TLEN / 16, BATCHN), 256, 0, stream>>>(
                h, hd, Wd + (size_t)i * HCH * 3, bd + (size_t)i * HCH,
                g1 + (size_t)i * HCH, be1 + (size_t)i * HCH,
                st_h, st_hd, a2 + i, dil);
            mm_k<HCH, EP_LAST><<<dim3(25, 1, BATCHN), 256, 0, stream>>>(
                hd, Wsr + (size_t)i * 256 * HCH,
                bskip + (size_t)i * BCH, uv_sr + (size_t)i * 2 * 256,
                nullptr, feats_bf, outAcc, st_hd, aout, BCH);
        }
    }

    mm_final_k<<<dim3(25, 8, BATCHN), 256, 0, stream>>>(
        feats_bf, Wob, bo, out);
}

// Round 10
// 1720.873 us; speedup vs baseline: 1.7614x; 1.7614x over previous
//
#include <hip/hip_runtime.h>
#include <cstdint>
#include <cstddef>

#define BATCHN 8
#define TLEN   3200
#define NCH    512
#define BCH    128
#define HCH    512
#define LBLK   24
#define CNTF   (512.0f * 3200.0f)
#define EPSV   1e-8f
#define NSLOT  32

typedef float  floatx4 __attribute__((ext_vector_type(4)));
typedef short  short8  __attribute__((ext_vector_type(8)));
typedef short  short4v __attribute__((ext_vector_type(4)));

enum { EP_FIRST = 1, EP_LAST = 2 };

__device__ inline unsigned short f2bf(float f) {
    unsigned int u = __float_as_uint(f);
    u = (u + 0x7fffu + ((u >> 16) & 1u)) >> 16;
    return (unsigned short)u;
}
__device__ inline float bf2f(short s) {
    return __uint_as_float(((unsigned int)(unsigned short)s) << 16);
}

// async global->LDS, 16B per lane; lds base must be wave-uniform.
__device__ inline void gload_lds16(const unsigned short* g, unsigned short* l) {
    __builtin_amdgcn_global_load_lds(
        (const __attribute__((address_space(1))) unsigned int*)(g),
        (__attribute__((address_space(3))) unsigned int*)(l),
        16, 0, 0);
}

__device__ inline void block_reduce_atomic2(float s, float ss, float* out) {
#pragma unroll
    for (int off = 32; off; off >>= 1) {
        s  += __shfl_down(s, off, 64);
        ss += __shfl_down(ss, off, 64);
    }
    __shared__ float pr[16];
    const int wave = threadIdx.x >> 6;
    const int lane = threadIdx.x & 63;
    if (lane == 0) { pr[wave * 2] = s; pr[wave * 2 + 1] = ss; }
    __syncthreads();
    if (threadIdx.x == 0) {
        const int nw = blockDim.x >> 6;
        float a = 0.f, b = 0.f;
        for (int i = 0; i < nw; i++) { a += pr[i * 2]; b += pr[i * 2 + 1]; }
        atomicAdd(out, a);
        atomicAdd(out + 1, b);
    }
}

__device__ inline void load_stats32(const float* __restrict__ st,
                                    float& mu, float& rstd) {
    float s = 0.f, ss = 0.f;
#pragma unroll
    for (int i = 0; i < NSLOT; i++) { s += st[2 * i]; ss += st[2 * i + 1]; }
    mu = s * (1.f / CNTF);
    const float var = ss * (1.f / CNTF) - mu * mu;
    rstd = rsqrtf(var + EPSV);
}

// ---------------------------------------------------------------------------
// mm_k: no-LDS MFMA GEMM (128t x 128c block, 4 waves 2x2 of 64x64) — used
// only for EP_FIRST / EP_LAST. Operand-SWAPPED MFMA: mfma(w, a) => D col =
// lane&15 -> t, row = quad*4+reg -> channel (float4/short4 epilogue).
// ---------------------------------------------------------------------------
template <int KDIM, int EP>
__global__ __launch_bounds__(256, 4) void mm_k(
    const unsigned short* __restrict__ X,
    const unsigned short* __restrict__ W,
    const float* __restrict__ bias, const float* __restrict__ uv,
    float* __restrict__ O_f32, unsigned short* __restrict__ O_bf,
    const float* __restrict__ outAcc_ro,
    const float* __restrict__ statsIn,
    const float* __restrict__ alphaPtr, int Cout)
{
    const int b    = blockIdx.z;
    const int t0   = blockIdx.x * 128;
    const int m0   = blockIdx.y * 128;
    const int lane = threadIdx.x & 63;
    const int wid  = threadIdx.x >> 6;
    const int wt   = wid & 1;
    const int wm   = wid >> 1;
    const int l15  = lane & 15;
    const int quad = lane >> 4;

    const unsigned short* Xb =
        X + ((size_t)b * TLEN + t0 + wt * 64 + l15) * KDIM + quad * 8;
    const unsigned short* Wb =
        W + (size_t)(m0 + wm * 64 + l15) * KDIM + quad * 8;

    floatx4 acc[4][4];
#pragma unroll
    for (int i = 0; i < 4; i++)
#pragma unroll
        for (int j = 0; j < 4; j++)
#pragma unroll
            for (int r = 0; r < 4; r++) acc[i][j][r] = 0.f;

#pragma unroll 2
    for (int kc = 0; kc < KDIM / 32; ++kc) {
        const int ko = kc * 32;
        short8 a[4], w[4];
#pragma unroll
        for (int i = 0; i < 4; i++)
            a[i] = *reinterpret_cast<const short8*>(Xb + (size_t)i * 16 * KDIM + ko);
#pragma unroll
        for (int j = 0; j < 4; j++)
            w[j] = *reinterpret_cast<const short8*>(Wb + (size_t)j * 16 * KDIM + ko);
#pragma unroll
        for (int i = 0; i < 4; i++)
#pragma unroll
            for (int j = 0; j < 4; j++)
                acc[i][j] = __builtin_amdgcn_mfma_f32_16x16x32_bf16(
                    w[j], a[i], acc[i][j], 0, 0, 0);
    }

    float mu = 0.f, rstd = 1.f, alpha = 0.f;
    load_stats32(statsIn + b * (2 * NSLOT), mu, rstd);
    if (EP == EP_LAST) alpha = alphaPtr[0];

#pragma unroll
    for (int j = 0; j < 4; j++) {
        const int cb = m0 + wm * 64 + j * 16 + quad * 4;   // 4 consecutive c
        const float4 b4 = *reinterpret_cast<const float4*>(bias + cb);
        const float4 u4 = *reinterpret_cast<const float4*>(uv + cb);
        const float4 v4 = *reinterpret_cast<const float4*>(
            uv + cb + (EP == EP_LAST ? 2 * BCH : Cout));
        float rb[4] = { b4.x + u4.x - mu * rstd * v4.x,
                        b4.y + u4.y - mu * rstd * v4.y,
                        b4.z + u4.z - mu * rstd * v4.z,
                        b4.w + u4.w - mu * rstd * v4.w };
#pragma unroll
        for (int i = 0; i < 4; i++) {
            const int t = t0 + wt * 64 + i * 16 + l15;
            const size_t idx = ((size_t)b * TLEN + t) * Cout + cb;
            if (EP == EP_FIRST) {
                float4 o;
                short4v s;
#pragma unroll
                for (int r = 0; r < 4; r++) {
                    const float val = rstd * acc[i][j][r] + rb[r];
                    (&o.x)[r] = val;
                    s[r] = (short)f2bf(val);
                }
                *reinterpret_cast<float4*>(O_f32 + idx) = o;
                *reinterpret_cast<short4v*>(O_bf + idx) = s;
            } else {   // EP_LAST
                const float4 oa = *reinterpret_cast<const float4*>(outAcc_ro + idx);
                short4v s;
#pragma unroll
                for (int r = 0; r < 4; r++) {
                    const float val = rstd * acc[i][j][r] + rb[r];
                    const float f = (&oa.x)[r] + val;
                    const float pv = f >= 0.f ? f : alpha * f;
                    s[r] = (short)f2bf(pv);
                }
                *reinterpret_cast<short4v*>(O_bf + idx) = s;
            }
        }
    }
}

// ---------------------------------------------------------------------------
// EP_H GEMM with LDS-staged A (layer 0 only): h = PReLU(W1 @ feats + b1).
// ---------------------------------------------------------------------------
__global__ __launch_bounds__(256, 4) void mm_h_lds_k(
    const unsigned short* __restrict__ X,   // feats_bf [b][t][128]
    const unsigned short* __restrict__ W,   // W1b [512][128]
    const float* __restrict__ bias,
    float* __restrict__ statsOut,
    const float* __restrict__ alphaPtr,
    unsigned short* __restrict__ O_bf)      // h [b][t][512]
{
    __shared__ unsigned short As[128 * 128];  // 32KB
    const int b    = blockIdx.z;
    const int t0   = blockIdx.x * 128;
    const int m0   = blockIdx.y * 128;
    const int lane = threadIdx.x & 63;
    const int wid  = threadIdx.x >> 6;
    const int wt   = wid & 1;
    const int wm   = wid >> 1;
    const int l15  = lane & 15;
    const int quad = lane >> 4;

#pragma unroll
    for (int q = 0; q < 8; q++) {
        const int r = wid * 32 + q * 4 + quad;
        const unsigned short* src =
            X + ((size_t)b * TLEN + t0 + r) * BCH + ((l15 ^ (r & 15)) * 8);
        gload_lds16(src, As + (wid * 32 + q * 4) * BCH);
    }
    __syncthreads();

    const unsigned short* Wb =
        W + (size_t)(m0 + wm * 64 + l15) * BCH + quad * 8;

    floatx4 acc[4][4];
#pragma unroll
    for (int i = 0; i < 4; i++)
#pragma unroll
        for (int j = 0; j < 4; j++)
#pragma unroll
            for (int r = 0; r < 4; r++) acc[i][j][r] = 0.f;

#pragma unroll
    for (int kc = 0; kc < 4; ++kc) {
        short8 a[4], w[4];
#pragma unroll
        for (int j = 0; j < 4; j++)
            w[j] = *reinterpret_cast<const short8*>(
                Wb + (size_t)j * 16 * BCH + kc * 32);
#pragma unroll
        for (int i = 0; i < 4; i++) {
            const int R  = wt * 64 + i * 16 + l15;     // R&15 == l15
            const int sl = (kc * 4 + quad) ^ l15;
            a[i] = *reinterpret_cast<const short8*>(As + R * BCH + sl * 8);
        }
#pragma unroll
        for (int i = 0; i < 4; i++)
#pragma unroll
            for (int j = 0; j < 4; j++)
                acc[i][j] = __builtin_amdgcn_mfma_f32_16x16x32_bf16(
                    w[j], a[i], acc[i][j], 0, 0, 0);
    }

    const float alpha = alphaPtr[0];
    float ssum = 0.f, ssq = 0.f;
#pragma unroll
    for (int j = 0; j < 4; j++) {
        const int cb = m0 + wm * 64 + j * 16 + quad * 4;   // 4 consecutive c
        const float4 b4 = *reinterpret_cast<const float4*>(bias + cb);
#pragma unroll
        for (int i = 0; i < 4; i++) {
            const int t = t0 + wt * 64 + i * 16 + l15;
            short4v s;
#pragma unroll
            for (int r = 0; r < 4; r++) {
                float val = acc[i][j][r] + (&b4.x)[r];
                val = val >= 0.f ? val : alpha * val;
                ssum += val; ssq += val * val;
                s[r] = (short)f2bf(val);
            }
            *reinterpret_cast<short4v*>(
                O_bf + ((size_t)b * TLEN + t) * HCH + cb) = s;
        }
    }
    block_reduce_atomic2(ssum, ssq,
        statsOut + b * (2 * NSLOT) +
        ((blockIdx.x + blockIdx.y * 25) & (NSLOT - 1)) * 2);
}

// ---------------------------------------------------------------------------
// FUSED dual(i) + mm_h(i+1): round-6 proven structure, 4 waves (256 thr),
// 64t x 256m block, with ONE-SHOT whole-tile LDS staging: the full 64x512
// A-tile (64KB) is staged via 16 back-to-back global_load_lds per wave and
// ONE barrier (was 4 chunks double-buffered with 4 barriers). Fewer
// vmcnt(0)+barrier drains, 4x deeper load queue. Occupancy unchanged
// (2 blocks/CU, LDS-limited).
// Epilogue: wm<2 -> skip (outAcc += f32x4), wm>=2 -> res (feats RMW + bf16
// deposit to LDS chunk 0). Phase 2 = mm_h(i+1) from the deposited tile.
// Wsr [256][512]: rows 0..127 = Wskip*g2, 128..255 = Wres*g2.
// uv [512]: u[0:256], v[256:512].
// ---------------------------------------------------------------------------
__global__ __launch_bounds__(256, 2) void mm_dual_h_k(
    const unsigned short* __restrict__ X,    // hd(i) [b][t][512]
    const unsigned short* __restrict__ Wsr,
    const float* __restrict__ bskip, const float* __restrict__ bres,
    const float* __restrict__ uv,
    float* __restrict__ feats,
    float* __restrict__ outAcc,
    const float* __restrict__ statsIn,       // st_hd(i)
    const unsigned short* __restrict__ W1,   // W1b(i+1) [512][128]
    const float* __restrict__ b1,
    const float* __restrict__ a1p,
    float* __restrict__ statsOut,            // st_h(i+1)
    unsigned short* __restrict__ h_out)      // h(i+1) [b][t][512]
{
    __shared__ unsigned short As[4 * 64 * 128];  // 64KB: 4 K-chunks x [64][128]
    const int b    = blockIdx.z;
    const int t0   = blockIdx.x * 64;
    const int lane = threadIdx.x & 63;
    const int wm   = threadIdx.x >> 6;   // 0..3 -> m-quarter
    const int l15  = lane & 15;
    const int quad = lane >> 4;

    const unsigned short* Wb =
        Wsr + (size_t)(wm * 64 + l15) * HCH + quad * 8;

    floatx4 acc[4][4];
#pragma unroll
    for (int i = 0; i < 4; i++)
#pragma unroll
        for (int j = 0; j < 4; j++)
#pragma unroll
            for (int r = 0; r < 4; r++) acc[i][j][r] = 0.f;

    // one-shot stage: whole 64x512 tile; wave wm stages rows [wm*16, wm*16+16)
    // of each K-chunk. 16 gloads per wave, single barrier.
    const int srow = wm * 16;
#pragma unroll
    for (int kc = 0; kc < 4; ++kc) {
#pragma unroll
        for (int q = 0; q < 4; q++) {
            const int r = srow + q * 4 + quad;
            const unsigned short* src =
                X + ((size_t)b * TLEN + t0 + r) * HCH + kc * 128 +
                ((l15 ^ (r & 15)) * 8);
            gload_lds16(src, As + kc * 8192 + (srow + q * 4) * 128);
        }
    }
    __syncthreads();

#pragma unroll
    for (int kc = 0; kc < 4; ++kc) {
        const unsigned short* Ab = As + kc * 8192;
#pragma unroll
        for (int ks = 0; ks < 4; ++ks) {
            short8 a[4], w[4];
#pragma unroll
            for (int j = 0; j < 4; j++)
                w[j] = *reinterpret_cast<const short8*>(
                    Wb + (size_t)j * 16 * HCH + kc * 128 + ks * 32);
#pragma unroll
            for (int i = 0; i < 4; i++) {
                const int R  = i * 16 + l15;          // R&15 == l15
                const int sl = (ks * 4 + quad) ^ l15;
                a[i] = *reinterpret_cast<const short8*>(Ab + R * 128 + sl * 8);
            }
#pragma unroll
            for (int i = 0; i < 4; i++)
#pragma unroll
                for (int j = 0; j < 4; j++)
                    acc[i][j] = __builtin_amdgcn_mfma_f32_16x16x32_bf16(
                        w[j], a[i], acc[i][j], 0, 0, 0);
        }
    }
    __syncthreads();   // all As reads done before deposit overwrites chunk 0

    float mu, rstd;
    load_stats32(statsIn + b * (2 * NSLOT), mu, rstd);

    const bool sk = (wm < 2);            // wave-uniform
#pragma unroll
    for (int j = 0; j < 4; j++) {
        const int c  = wm * 64 + j * 16 + quad * 4;  // 0..255 combined
        const int cc = sk ? c : c - 128;
        const float4 b4 = sk
            ? *reinterpret_cast<const float4*>(bskip + cc)
            : *reinterpret_cast<const float4*>(bres + cc);
        const float4 u4 = *reinterpret_cast<const float4*>(uv + c);
        const float4 v4 = *reinterpret_cast<const float4*>(uv + c + 256);
        float rb[4] = { b4.x + u4.x - mu * rstd * v4.x,
                        b4.y + u4.y - mu * rstd * v4.y,
                        b4.z + u4.z - mu * rstd * v4.z,
                        b4.w + u4.w - mu * rstd * v4.w };
#pragma unroll
        for (int i = 0; i < 4; i++) {
            const int t = t0 + i * 16 + l15;
            const size_t idx = ((size_t)b * TLEN + t) * BCH + cc;
            if (sk) {
                float4 oa = *reinterpret_cast<const float4*>(outAcc + idx);
#pragma unroll
                for (int r = 0; r < 4; r++)
                    (&oa.x)[r] += rstd * acc[i][j][r] + rb[r];
                *reinterpret_cast<float4*>(outAcc + idx) = oa;
            } else {
                float4 f = *reinterpret_cast<const float4*>(feats + idx);
                short4v s;
#pragma unroll
                for (int r = 0; r < 4; r++) {
                    (&f.x)[r] += rstd * acc[i][j][r] + rb[r];
                    s[r] = (short)f2bf((&f.x)[r]);
                }
                *reinterpret_cast<float4*>(feats + idx) = f;
                // deposit bf16 feats into As chunk 0, staging swizzle:
                // slot = (c>>3) ^ (row&15)
                const int row = i * 16 + l15;           // row&15 == l15
                const int sl  = (cc >> 3) ^ l15;
                *reinterpret_cast<short4v*>(
                    As + row * 128 + sl * 8 + (cc & 7)) = s;
            }
        }
    }
    __syncthreads();

    // -------- phase 2: h(i+1) = PReLU(W1 @ feats_tile + b1) --------
    const float alpha1 = a1p[0];
    float ssum = 0.f, ssq = 0.f;
#pragma unroll
    for (int mc = 0; mc < 2; ++mc) {
        const int mb = wm * 128 + mc * 64;
        const unsigned short* W1p =
            W1 + (size_t)(mb + l15) * BCH + quad * 8;

        floatx4 acc2[4][4];
#pragma unroll
        for (int i = 0; i < 4; i++)
#pragma unroll
            for (int j = 0; j < 4; j++)
#pragma unroll
                for (int r = 0; r < 4; r++) acc2[i][j][r] = 0.f;

#pragma unroll
        for (int kc = 0; kc < 4; ++kc) {
            short8 a[4], w[4];
#pragma unroll
            for (int j = 0; j < 4; j++)
                w[j] = *reinterpret_cast<const short8*>(
                    W1p + (size_t)j * 16 * BCH + kc * 32);
#pragma unroll
            for (int i = 0; i < 4; i++) {
                const int R  = i * 16 + l15;
                const int sl = (kc * 4 + quad) ^ l15;
                a[i] = *reinterpret_cast<const short8*>(As + R * 128 + sl * 8);
            }
#pragma unroll
            for (int i = 0; i < 4; i++)
#pragma unroll
                for (int j = 0; j < 4; j++)
                    acc2[i][j] = __builtin_amdgcn_mfma_f32_16x16x32_bf16(
                        w[j], a[i], acc2[i][j], 0, 0, 0);
        }

#pragma unroll
        for (int j = 0; j < 4; j++) {
            const int cb = mb + j * 16 + quad * 4;
            const float4 b4 = *reinterpret_cast<const float4*>(b1 + cb);
#pragma unroll
            for (int i = 0; i < 4; i++) {
                const int t = t0 + i * 16 + l15;
                short4v s;
#pragma unroll
                for (int r = 0; r < 4; r++) {
                    float val = acc2[i][j][r] + (&b4.x)[r];
                    val = val >= 0.f ? val : alpha1 * val;
                    ssum += val; ssq += val * val;
                    s[r] = (short)f2bf(val);
                }
                *reinterpret_cast<short4v*>(
                    h_out + ((size_t)b * TLEN + t) * HCH + cb) = s;
            }
        }
    }
    block_reduce_atomic2(ssum, ssq,
        statsOut + b * (2 * NSLOT) + (blockIdx.x & (NSLOT - 1)) * 2);
}

// Final GEMM: out[b][m][t] = sigmoid(Wo @ Xbf + bo).
__global__ __launch_bounds__(256, 4) void mm_final_k(
    const unsigned short* __restrict__ Xbf, const unsigned short* __restrict__ Wb,
    const float* __restrict__ bo, float* __restrict__ out)
{
    const int b    = blockIdx.z;
    const int t0   = blockIdx.x * 128;
    const int m0   = blockIdx.y * 128;
    const int lane = threadIdx.x & 63;
    const int wid  = threadIdx.x >> 6;
    const int wc   = wid & 1;    // t half
    const int wr   = wid >> 1;   // m half
    const int l15  = lane & 15;
    const int quad = lane >> 4;

    const unsigned short* Wp =
        Wb + (size_t)(m0 + wr * 64 + l15) * BCH + quad * 8;
    const unsigned short* Xp =
        Xbf + ((size_t)b * TLEN + t0 + wc * 64 + l15) * BCH + quad * 8;

    floatx4 acc[4][4];
#pragma unroll
    for (int i = 0; i < 4; i++)
#pragma unroll
        for (int j = 0; j < 4; j++)
#pragma unroll
            for (int r = 0; r < 4; r++) acc[i][j][r] = 0.f;

#pragma unroll 2
    for (int kc = 0; kc < BCH / 32; ++kc) {
        const int ko = kc * 32;
        short8 a[4], x[4];
#pragma unroll
        for (int i = 0; i < 4; i++)
            a[i] = *reinterpret_cast<const short8*>(Wp + (size_t)i * 16 * BCH + ko);
#pragma unroll
        for (int j = 0; j < 4; j++)
            x[j] = *reinterpret_cast<const short8*>(Xp + (size_t)j * 16 * BCH + ko);
#pragma unroll
        for (int i = 0; i < 4; i++)
#pragma unroll
            for (int j = 0; j < 4; j++)
                acc[i][j] = __builtin_amdgcn_mfma_f32_16x16x32_bf16(
                    a[i], x[j], acc[i][j], 0, 0, 0);
    }

#pragma unroll
    for (int i = 0; i < 4; i++) {
        const int mb = m0 + wr * 64 + i * 16 + quad * 4;
#pragma unroll
        for (int r = 0; r < 4; r++) {
            const int m = mb + r;
            const float bz = bo[m];
#pragma unroll
            for (int j = 0; j < 4; j++) {
                const int t = t0 + wc * 64 + j * 16 + l15;
                const float val = acc[i][j][r] + bz;
                const float e = __expf(-val);
                out[((size_t)b * (2 * NCH) + m) * TLEN + t] =
                    __builtin_amdgcn_rcpf(1.f + e);
            }
        }
    }
}

// Weight prep: bf16 convert with optional per-column gLN gamma fold, plus
// u = W @ be, v = W @ g row-vectors. One wave per row.
__global__ __launch_bounds__(256) void prep_w_k(
    const float* __restrict__ W, const float* __restrict__ g,
    const float* __restrict__ be, unsigned short* __restrict__ Wout,
    float* __restrict__ uv, int Mrows, int K, int nmat, int Mout, int rowOff)
{
    const int r    = blockIdx.x * 4 + (threadIdx.x >> 6);
    const int lane = threadIdx.x & 63;
    if (r >= Mrows * nmat) return;
    const int mat = r / Mrows;
    const int m   = r - mat * Mrows;
    const float* Wrow = W + (size_t)r * K;
    const float* gv = g  ? g  + (size_t)mat * K : nullptr;
    const float* bv = be ? be + (size_t)mat * K : nullptr;
    unsigned short* orow = Wout + ((size_t)mat * Mout + rowOff + m) * K;
    float u = 0.f, v = 0.f;
    for (int k = lane * 4; k < K; k += 256) {
        float4 w4 = *reinterpret_cast<const float4*>(Wrow + k);
        float4 o4 = w4;
        if (gv) {
            const float4 g4 = *reinterpret_cast<const float4*>(gv + k);
            const float4 b4 = *reinterpret_cast<const float4*>(bv + k);
            o4.x = w4.x * g4.x; o4.y = w4.y * g4.y;
            o4.z = w4.z * g4.z; o4.w = w4.w * g4.w;
            u += w4.x * b4.x + w4.y * b4.y + w4.z * b4.z + w4.w * b4.w;
            v += w4.x * g4.x + w4.y * g4.y + w4.z * g4.z + w4.w * g4.w;
        }
        short4v s;
        s[0] = (short)f2bf(o4.x); s[1] = (short)f2bf(o4.y);
        s[2] = (short)f2bf(o4.z); s[3] = (short)f2bf(o4.w);
        *reinterpret_cast<short4v*>(orow + k) = s;
    }
    if (gv && uv) {
#pragma unroll
        for (int off = 32; off; off >>= 1) {
            u += __shfl_down(u, off, 64);
            v += __shfl_down(v, off, 64);
        }
        if (lane == 0) {
            uv[(size_t)mat * 2 * Mout + rowOff + m]        = u;
            uv[(size_t)mat * 2 * Mout + Mout + rowOff + m] = v;
        }
    }
}

// Transpose + bf16 cvt + x-stats (fused).
__global__ __launch_bounds__(256) void tr_x_k(
    const float* __restrict__ x, unsigned short* __restrict__ xt,
    float* __restrict__ statsOut)
{
    __shared__ unsigned short tile[32][33];
    const int b  = blockIdx.z;
    const int t0 = blockIdx.x * 32;
    const int c0 = blockIdx.y * 32;
    const int tx = threadIdx.x & 31;
    const int ty = threadIdx.x >> 5;

    float s = 0.f, ss = 0.f;
#pragma unroll
    for (int r = 0; r < 4; r++) {
        const int cl = ty + r * 8;
        const float v = x[((size_t)b * NCH + c0 + cl) * TLEN + t0 + tx];
        s += v; ss += v * v;
        tile[tx][cl] = f2bf(v);
    }
    __syncthreads();
#pragma unroll
    for (int r = 0; r < 4; r++) {
        const int tl = ty + r * 8;
        xt[((size_t)b * TLEN + t0 + tl) * NCH + c0 + tx] = tile[tl][tx];
    }
    block_reduce_atomic2(s, ss,
        statsOut + b * (2 * NSLOT) +
        ((blockIdx.x + blockIdx.y * 25) & (NSLOT - 1)) * 2);
}

// Depthwise dilated conv, gLN folded, + bd, PReLU(a2), stats. 4 t-rows/wave.
__global__ __launch_bounds__(256) void dwconv_k(
    const unsigned short* __restrict__ h, unsigned short* __restrict__ hd,
    const float* __restrict__ Wd, const float* __restrict__ bd,
    const float* __restrict__ g1, const float* __restrict__ be1,
    const float* __restrict__ statsIn, float* __restrict__ statsOut,
    const float* __restrict__ a2p, int dil)
{
    const int b  = blockIdx.y;
    const int tb = blockIdx.x * 16 + (threadIdx.x >> 6) * 4;
    const int c0 = (threadIdx.x & 63) * 8;

    float mu, rstd;
    load_stats32(statsIn + b * (2 * NSLOT), mu, rstd);
    const float alpha = a2p[0];

    float g[8], be[8], bz[8], wall[24];
#pragma unroll
    for (int q = 0; q < 6; q++) {
        const float4 w4 = *reinterpret_cast<const float4*>(Wd + (size_t)c0 * 3 + q * 4);
        wall[q * 4 + 0] = w4.x; wall[q * 4 + 1] = w4.y;
        wall[q * 4 + 2] = w4.z; wall[q * 4 + 3] = w4.w;
    }
    {
        const float4 ga = *reinterpret_cast<const float4*>(g1 + c0);
        const float4 gb = *reinterpret_cast<const float4*>(g1 + c0 + 4);
        const float4 ba = *reinterpret_cast<const float4*>(be1 + c0);
        const float4 bb = *reinterpret_cast<const float4*>(be1 + c0 + 4);
        const float4 da = *reinterpret_cast<const float4*>(bd + c0);
        const float4 db = *reinterpret_cast<const float4*>(bd + c0 + 4);
        const float gg[8] = { ga.x, ga.y, ga.z, ga.w, gb.x, gb.y, gb.z, gb.w };
        const float bbv[8] = { ba.x, ba.y, ba.z, ba.w, bb.x, bb.y, bb.z, bb.w };
        const float dd[8] = { da.x, da.y, da.z, da.w, db.x, db.y, db.z, db.w };
#pragma unroll
        for (int jj = 0; jj < 8; jj++) {
            g[jj]  = gg[jj] * rstd;
            be[jj] = bbv[jj] - mu * rstd * gg[jj];
            bz[jj] = dd[jj];
        }
    }

    float psum = 0.f, psq = 0.f;
#pragma unroll
    for (int it = 0; it < 4; ++it) {
        const int t = tb + it;
        const size_t rowb = ((size_t)b * TLEN + t) * HCH + c0;
        const bool hasP = (t - dil) >= 0;
        const bool hasN = (t + dil) < TLEN;
        const short8 cur = *reinterpret_cast<const short8*>(h + rowb);
        short8 prv = {}, nxt = {};
        if (hasP) prv = *reinterpret_cast<const short8*>(h + rowb - (size_t)dil * HCH);
        if (hasN) nxt = *reinterpret_cast<const short8*>(h + rowb + (size_t)dil * HCH);

        short8 o;
#pragma unroll
        for (int jj = 0; jj < 8; jj++) {
            float acc = bz[jj] + wall[jj * 3 + 1] * (g[jj] * bf2f(cur[jj]) + be[jj]);
            if (hasP) acc += wall[jj * 3 + 0] * (g[jj] * bf2f(prv[jj]) + be[jj]);
            if (hasN) acc += wall[jj * 3 + 2] * (g[jj] * bf2f(nxt[jj]) + be[jj]);
            const float v = acc >= 0.f ? acc : alpha * acc;
            o[jj] = (short)f2bf(v);
            psum += v; psq += v * v;
        }
        *reinterpret_cast<short8*>(hd + rowb) = o;
    }
    block_reduce_atomic2(psum, psq,
        statsOut + b * (2 * NSLOT) + (blockIdx.x & (NSLOT - 1)) * 2);
}

extern "C" void kernel_launch(void* const* d_in, const int* in_sizes, int n_in,
                              void* d_out, int out_size, void* d_ws, size_t ws_size,
                              hipStream_t stream)
{
    (void)in_sizes; (void)n_in; (void)out_size; (void)ws_size;

    const float* x    = (const float*)d_in[0];
    const float* in_g = (const float*)d_in[1];
    const float* in_b = (const float*)d_in[2];
    const float* Wc   = (const float*)d_in[3];
    const float* bc   = (const float*)d_in[4];
    const float* W1   = (const float*)d_in[5];
    const float* b1   = (const float*)d_in[6];
    const float* a1   = (const float*)d_in[7];
    const float* g1   = (const float*)d_in[8];
    const float* be1  = (const float*)d_in[9];
    const float* Wd   = (const float*)d_in[10];
    const float* bd   = (const float*)d_in[11];
    const float* a2   = (const float*)d_in[12];
    const float* g2   = (const float*)d_in[13];
    const float* be2  = (const float*)d_in[14];
    const float* Wres = (const float*)d_in[15];
    const float* bres = (const float*)d_in[16];
    const float* Wskip= (const float*)d_in[17];
    const float* bskip= (const float*)d_in[18];
    const float* aout = (const float*)d_in[19];
    const float* Wo   = (const float*)d_in[20];
    const float* bo   = (const float*)d_in[21];
    float* out = (float*)d_out;

    // workspace carve-up (bytes, 16B-aligned regions)
    uint8_t* p = (uint8_t*)d_ws;
    unsigned short* x_t      = (unsigned short*)p; p += (size_t)BATCHN*TLEN*NCH*2;
    float*          feats    = (float*)p;          p += (size_t)BATCHN*TLEN*BCH*4;
    unsigned short* feats_bf = (unsigned short*)p; p += (size_t)BATCHN*TLEN*BCH*2;
    float*          outAcc   = (float*)p;          p += (size_t)BATCHN*TLEN*BCH*4;
    unsigned short* h        = (unsigned short*)p; p += (size_t)BATCHN*TLEN*HCH*2;
    unsigned short* hd       = (unsigned short*)p; p += (size_t)BATCHN*TLEN*HCH*2;
    unsigned short* WcG      = (unsigned short*)p; p += (size_t)BCH*NCH*2;
    unsigned short* W1b      = (unsigned short*)p; p += (size_t)LBLK*HCH*BCH*2;
    unsigned short* Wsr      = (unsigned short*)p; p += (size_t)LBLK*256*HCH*2;
    unsigned short* Wob      = (unsigned short*)p; p += (size_t)(2*NCH)*BCH*2;
    float*          uv_c     = (float*)p;          p += (size_t)2*BCH*4;
    float*          uv_sr    = (float*)p;          p += (size_t)LBLK*2*256*4;
    float*          stats    = (float*)p;

    const size_t SLOTF = (size_t)BATCHN * 2 * NSLOT;  // floats per stat slot

    hipMemsetAsync(stats, 0, (size_t)49 * SLOTF * sizeof(float), stream);
    hipMemsetAsync(outAcc, 0, (size_t)BATCHN*TLEN*BCH*sizeof(float), stream);

    // ---- prep ----
    tr_x_k<<<dim3(100, 16, BATCHN), 256, 0, stream>>>(x, x_t, stats);
    prep_w_k<<<32,   256, 0, stream>>>(Wc,   in_g,    in_b,    WcG, uv_c, BCH,   NCH, 1,      BCH, 0);
    prep_w_k<<<3072, 256, 0, stream>>>(W1,   nullptr, nullptr, W1b, nullptr, HCH, BCH, LBLK,  HCH, 0);
    prep_w_k<<<768,  256, 0, stream>>>(Wskip,g2,      be2,     Wsr, uv_sr, BCH,  HCH, LBLK,   256, 0);
    prep_w_k<<<736,  256, 0, stream>>>(Wres, g2,      be2,     Wsr, uv_sr, BCH,  HCH, LBLK-1, 256, 128);
    prep_w_k<<<256,  256, 0, stream>>>(Wo,   nullptr, nullptr, Wob, nullptr, 2*NCH, BCH, 1,   2*NCH, 0);

    // ---- first: feats = rstd*(WcG @ x_t) + rowbias ----
    mm_k<NCH, EP_FIRST><<<dim3(25, 1, BATCHN), 256, 0, stream>>>(
        x_t, WcG, bc, uv_c, feats, feats_bf, nullptr, stats, nullptr, BCH);

    // ---- layer 0 mm_h (standalone) ----
    mm_h_lds_k<<<dim3(25, 4, BATCHN), 256, 0, stream>>>(
        feats_bf, W1b, b1, stats + SLOTF, a1, h);

    for (int i = 0; i < LBLK; i++) {
        float* st_h  = stats + (size_t)(1 + 2 * i) * SLOTF;
        float* st_hd = stats + (size_t)(2 + 2 * i) * SLOTF;
        const int dil = 1 << (i & 7);

        dwconv_k<<<dim3(TLEN / 16, BATCHN), 256, 0, stream>>>(
            h, hd, Wd + (size_t)i * HCH * 3, bd + (size_t)i * HCH,
            g1 + (size_t)i * HCH, be1 + (size_t)i * HCH,
            st_h, st_hd, a2 + i, dil);

        if (i < LBLK - 1) {
            // fused dual(i) + mm_h(i+1)
            mm_dual_h_k<<<dim3(50, 1, BATCHN), 256, 0, stream>>>(
                hd, Wsr + (size_t)i * 256 * HCH,
                bskip + (size_t)i * BCH, bres + (size_t)i * BCH,
                uv_sr + (size_t)i * 2 * 256,
                feats, outAcc, st_hd,
                W1b + (size_t)(i + 1) * HCH * BCH,
                b1 + (size_t)(i + 1) * HCH, a1 + (i + 1),
                stats + (size_t)(1 + 2 * (i + 1)) * SLOTF, h);
        } else {
            mm_k<HCH, EP_LAST><<<dim3(25, 1, BATCHN), 256, 0, stream>>>(
                hd, Wsr + (size_t)i * 256 * HCH,
                bskip + (size_t)i * BCH, uv_sr + (size_t)i * 2 * 256,
                nullptr, feats_bf, outAcc, st_hd, aout, BCH);
        }
    }

    mm_final_k<<<dim3(25, 8, BATCHN), 256, 0, stream>>>(
        feats_bf, Wob, bo, out);
}